// Round 4
// baseline (411.719 us; speedup 1.0000x reference)
//
#include <hip/hip_runtime.h>

typedef unsigned int u32;
typedef __bf16 bf16x8 __attribute__((ext_vector_type(8)));
typedef float f32x4 __attribute__((ext_vector_type(4)));

#define B_DIM 4
#define E_DIM 200000
#define C_OUT 64
#define TPB   12500            // 16-edge tiles per batch
#define NBLK  1280             // 160 blocks per XCD; 320 blocks per batch
#define BPB   (NBLK / B_DIM)   // 320 blocks/batch
#define TSTRIDE (BPB * 4)      // 1280 waves per batch -> tile stride
#define WLDS_U4 1792           // weight LDS: 7 chunks * 4 quads * 64 outs uint4

// round-half-up bf16 pack of two floats -> packed u32 (lo in low half).
// float is sign-magnitude, so +0x8000 on the bit pattern rounds the magnitude.
__device__ __forceinline__ u32 pack_bf2(float lo, float hi) {
  u32 a = __float_as_uint(lo) + 0x8000u;
  u32 b = __float_as_uint(hi) + 0x8000u;
  return __builtin_amdgcn_perm(b, a, 0x07060302u);  // [hi16(b) : hi16(a)]
}

// |bf16(a_i) - bf16(b_i)| for a packed pair, result packed bf16.
__device__ __forceinline__ u32 absdiff_pack(u32 a, u32 b) {
  float alo = __uint_as_float(a << 16), ahi = __uint_as_float(a & 0xffff0000u);
  float blo = __uint_as_float(b << 16), bhi = __uint_as_float(b & 0xffff0000u);
  u32 dlo = __float_as_uint(alo - blo) + 0x8000u;
  u32 dhi = __float_as_uint(ahi - bhi) + 0x8000u;
  return __builtin_amdgcn_perm(dhi, dlo, 0x07060302u) & 0x7fff7fffu;
}

__device__ __forceinline__ uint4 absdiff_vec(uint4 a, uint4 b) {
  return make_uint4(absdiff_pack(a.x, b.x), absdiff_pack(a.y, b.y),
                    absdiff_pack(a.z, b.z), absdiff_pack(a.w, b.w));
}

// ---- kernel 1: x (B,C,E) f32 -> xT (B,E,C) packed bf16; row = 64 B ----------
// LDS-staged: both global reads and global writes fully coalesced. (proven)
__global__ __launch_bounds__(256) void xpose_kernel(const float* __restrict__ x,
                                                    u32* __restrict__ xT) {
  __shared__ u32 T[256 * 17];  // pitch 17: conflict-free scattered writes
  const int b = blockIdx.y;
  const int e0 = blockIdx.x * 256;
  const int t = threadIdx.x;
  const int nrows = min(256, E_DIM - e0);
  const float* xb = x + (size_t)b * 32 * E_DIM + e0;
  if (t < nrows) {
#pragma unroll
    for (int u = 0; u < 16; ++u) {
      const float lo = xb[(size_t)(2 * u) * E_DIM + t];      // coalesced
      const float hi = xb[(size_t)(2 * u + 1) * E_DIM + t];
      T[t * 17 + u] = pack_bf2(lo, hi);
    }
  }
  __syncthreads();
  const int total = nrows * 16;
  u32* dst = xT + ((size_t)b * E_DIM + e0) * 16;
#pragma unroll
  for (int k = 0; k < 16; ++k) {
    const int g = t + k * 256;
    if (g < total) dst[g] = T[(g >> 4) * 17 + (g & 15)];     // coalesced store
  }
}

// ---- kernel 2: MFMA main, 16 edges x 64 outs per wave-tile ------------------
// Batch-partitioned XCD mapping: xcd = blockIdx&7, batch = xcd>>1. Each XCD's
// resident blocks gather only from their batch's 12.8 MB xT slice (L2 = 4 MB
// -> ~30% hit vs ~0 when batches mix). batch is loop-invariant, so the hot
// loop has NO divisions (r3's t/TPB magic-mul temps are gone).
// Prologue prep_w merged but unroll-capped: r3's full unroll batched ~56
// global loads -> VGPR peak 108 -> lost the 5th block/CU. Target: <=96 VGPR.
// VGPR discipline: no __launch_bounds__ 2nd arg (r2: (256,4) forced 64 regs
// -> catastrophic spills), bias via LDS not persistent regs.
__global__ __launch_bounds__(256) void mesh_main(const u32* __restrict__ xT,
                                                 const int* __restrict__ Gi,
                                                 const float* __restrict__ W,
                                                 const float* __restrict__ bias,
                                                 float* __restrict__ out) {
  __shared__ uint4 Wl[WLDS_U4];  // 28 KB
  __shared__ float Bl[64];       // bias

  // ---- prologue: swizzled bf16 weights + bias -> LDS -----------------------
  // Wl_flat[((s*4+q)*64 + o)*4 + r] = pack(W[o][q*8+2r][kk], W[o][q*8+2r+1][kk])
  // K-chunks s=0..6 multiply {f0, f1, f2, f3, f4, |f1-f3|, |f2-f4|}
  {
    u32* wl = (u32*)&Wl[0];
#pragma unroll 4
    for (int k = 0; k < 28; ++k) {
      const int p = (int)threadIdx.x + k * 256;  // < 7168
      const int r = p & 3;
      const int o = (p >> 2) & 63;
      const int qq = (p >> 8) & 3;
      const int s = p >> 10;
      const int kk = s < 3 ? s : s - 2;          // {0,1,2,1,2,3,4}
      const int c0 = qq * 8 + 2 * r;
      const float w0 = W[(o * 32 + c0) * 5 + kk];
      const float w1 = W[(o * 32 + c0 + 1) * 5 + kk];
      wl[p] = pack_bf2(w0, w1);
    }
    if (threadIdx.x < 64) Bl[threadIdx.x] = bias[threadIdx.x];
  }
  __syncthreads();

  const int l = (int)threadIdx.x & 63;
  const int wv = (int)threadIdx.x >> 6;
  const int n = l & 15;   // edge-in-tile == B-frag column
  const int q = l >> 4;   // quad == gather j4 == B-frag k-group

  // ---- XCD-aware batch partition ------------------------------------------
  const int xcd = (int)blockIdx.x & 7;
  const int blk = (int)blockIdx.x >> 3;          // 0..159 within XCD
  const int batch = xcd >> 1;                    // 0..3
  const int idx = (xcd & 1) * (BPB / 2) + blk;   // 0..319 within batch

  const uint4* xb4 = (const uint4*)(xT + (size_t)batch * E_DIM * 16);
  const int* Gib = Gi + (size_t)batch * E_DIM * 5;
  float* outb = out + (size_t)batch * C_OUT * E_DIM;

  int lt = idx * 4 + wv;   // local tile in [0, 1280); stride TSTRIDE

  // ---- pipeline prologue: Gi(lt) -> gather(lt) -> Gi(lt+TSTRIDE) ----
  int gcur[5], gnext[5];
  {
    const int* gp = Gib + (lt * 16 + n) * 5;
#pragma unroll
    for (int s = 0; s < 5; ++s) gcur[s] = gp[s];
  }
  uint4 cur[5];
#pragma unroll
  for (int s = 0; s < 5; ++s) cur[s] = xb4[(size_t)gcur[s] * 4 + q];

  int lt1 = lt + TSTRIDE;
  if (lt1 < TPB) {
    const int* gp = Gib + (lt1 * 16 + n) * 5;
#pragma unroll
    for (int s = 0; s < 5; ++s) gnext[s] = gp[s];
  }

  for (;;) {
    const bool has = lt1 < TPB;  // wave-uniform
    // stage B: gather tile lt1 (Gi already resident for >=1 iteration)
    uint4 nxt[5];
    if (has) {
#pragma unroll
      for (int s = 0; s < 5; ++s) nxt[s] = xb4[(size_t)gnext[s] * 4 + q];
    }
    // stage A: Gi for tile lt1+TSTRIDE
    const int lt2 = lt1 + TSTRIDE;
    if (lt2 < TPB) {
      const int* gp = Gib + (lt2 * 16 + n) * 5;
#pragma unroll
      for (int s = 0; s < 5; ++s) gnext[s] = gp[s];
    }

    // stage C: compute tile lt
    union U { uint4 u; bf16x8 v; };
    U frag[7];
#pragma unroll
    for (int s = 0; s < 5; ++s) frag[s].u = cur[s];
    frag[5].u = absdiff_vec(cur[1], cur[3]);
    frag[6].u = absdiff_vec(cur[2], cur[4]);

    f32x4 acc0 = *(const f32x4*)&Bl[0 * 16 + q * 4];
    f32x4 acc1 = *(const f32x4*)&Bl[1 * 16 + q * 4];
    f32x4 acc2 = *(const f32x4*)&Bl[2 * 16 + q * 4];
    f32x4 acc3 = *(const f32x4*)&Bl[3 * 16 + q * 4];
#pragma unroll
    for (int c = 0; c < 7; ++c) {
      const uint4* wp = Wl + (c * 4 + q) * 64 + n;
      U a0, a1;
      a0.u = wp[0];
      a1.u = wp[16];
      acc0 = __builtin_amdgcn_mfma_f32_16x16x32_bf16(a0.v, frag[c].v, acc0, 0, 0, 0);
      acc1 = __builtin_amdgcn_mfma_f32_16x16x32_bf16(a1.v, frag[c].v, acc1, 0, 0, 0);
      a0.u = wp[32];
      a1.u = wp[48];
      acc2 = __builtin_amdgcn_mfma_f32_16x16x32_bf16(a0.v, frag[c].v, acc2, 0, 0, 0);
      acc3 = __builtin_amdgcn_mfma_f32_16x16x32_bf16(a1.v, frag[c].v, acc3, 0, 0, 0);
    }

    // store: o = og*16 + q*4 + r, e = lt*16 + n
    {
      float* ob = outb + ((size_t)(q * 4) * E_DIM + lt * 16 + n);
#pragma unroll
      for (int r = 0; r < 4; ++r) {
        ob[(size_t)(0 * 16 + r) * E_DIM] = acc0[r];
        ob[(size_t)(1 * 16 + r) * E_DIM] = acc1[r];
        ob[(size_t)(2 * 16 + r) * E_DIM] = acc2[r];
        ob[(size_t)(3 * 16 + r) * E_DIM] = acc3[r];
      }
    }

    if (!has) break;
    lt = lt1;
    lt1 = lt2;
#pragma unroll
    for (int s = 0; s < 5; ++s) cur[s] = nxt[s];
  }
}

extern "C" void kernel_launch(void* const* d_in, const int* in_sizes, int n_in,
                              void* d_out, int out_size, void* d_ws, size_t ws_size,
                              hipStream_t stream) {
  const float* x    = (const float*)d_in[0];
  const int*   Gi   = (const int*)d_in[1];
  const float* W    = (const float*)d_in[2];
  const float* bias = (const float*)d_in[3];
  float* out = (float*)d_out;

  // workspace: xT packed-bf16 rows (B*E*16 u32 = 51.2 MB)
  u32* xT = (u32*)d_ws;

  dim3 gx((E_DIM + 255) / 256, B_DIM);
  xpose_kernel<<<gx, 256, 0, stream>>>(x, xT);

  mesh_main<<<NBLK, 256, 0, stream>>>(xT, Gi, W, bias, out);
}